// Round 10
// baseline (227.704 us; speedup 1.0000x reference)
//
#include <hip/hip_runtime.h>
#include <math.h>
#include <stdint.h>

#define S 2048
#define DMOD 1024
#define H 16

typedef unsigned short ushort_t;
typedef short bf16x8 __attribute__((ext_vector_type(8)));
typedef float f32x4 __attribute__((ext_vector_type(4)));

// chunk swizzle: rows 1..7 apart and 8 apart land on different chunk columns
#define SW(r) ((((r) & 7)) ^ ((((r) >> 3) & 3) << 1))

__device__ __forceinline__ ushort_t f2b(float f) {
    union { float f; unsigned u; } x; x.f = f;
    return (ushort_t)((x.u + 0x7FFFu + ((x.u >> 16) & 1u)) >> 16);
}
// round-half-up bf16 (2 ops); differs from RNE only on exact-tie mantissas
__device__ __forceinline__ ushort_t f2b_fast(float f) {
    union { float f; unsigned u; } x; x.f = f;
    return (ushort_t)((x.u + 0x8000u) >> 16);
}
__device__ __forceinline__ float b2f(ushort_t b) {
    union { unsigned u; float f; } x; x.u = ((unsigned)b) << 16;
    return x.f;
}
__device__ __forceinline__ void gld16(const ushort_t* g, ushort_t* l) {
    __builtin_amdgcn_global_load_lds(
        (const __attribute__((address_space(1))) unsigned int*)g,
        (__attribute__((address_space(3))) unsigned int*)l, 16, 0, 0);
}

// ---------------------------------------------------------------------------
// prep_all = convert + init merged. All destination regions are DISJOINT
// (attn_raw lives at ws+9M1, past every bf16 buffer).
// ---------------------------------------------------------------------------
__global__ __launch_bounds__(256) void prep_all(
    const float* q, const float* k, const float* v,
    const float* wq, const float* wk, const float* wv, const float* wo,
    ushort_t* qo, ushort_t* ko, ushort_t* vo,
    ushort_t* wqo, ushort_t* wko, ushort_t* wvo, ushort_t* woo,
    float* __restrict__ attn_raw, float* __restrict__ out,
    float* __restrict__ sumexp, float* __restrict__ corr)
{
    const int seg = blockIdx.y;
    const int bx = blockIdx.x;
    if (seg >= 10) {
        const float4 z4 = {0.f, 0.f, 0.f, 0.f};
        if (seg < 12) {
            *(float4*)(attn_raw + (((size_t)(seg - 10) * 1024 + bx) * 256 + threadIdx.x) * 4) = z4;
        } else if (seg < 14) {
            *(float4*)(out + (((size_t)(seg - 12) * 1024 + bx) * 256 + threadIdx.x) * 4) = z4;
        } else if (bx < 32) {
            int e = (bx * 256 + threadIdx.x) * 4;
            float4 vv = {(float)(e & 2047), (float)((e + 1) & 2047),
                         (float)((e + 2) & 2047), (float)((e + 3) & 2047)};
            *(float4*)(sumexp + e) = vv;
        } else if (bx == 32) {
            *(float4*)(corr + threadIdx.x * 4) = z4;
        }
        return;
    }
    const float* src; ushort_t* dst; size_t off = 0;
    const size_t M1 = (size_t)1 << 20;
    if (seg < 2)       { src = q;  dst = qo;  off = (size_t)seg * M1; }
    else if (seg < 4)  { src = k;  dst = ko;  off = (size_t)(seg - 2) * M1; }
    else if (seg < 6)  { src = v;  dst = vo;  off = (size_t)(seg - 4) * M1; }
    else if (seg == 6) { src = wq; dst = wqo; }
    else if (seg == 7) { src = wk; dst = wko; }
    else if (seg == 8) { src = wv; dst = wvo; }
    else               { src = wo; dst = woo; }
    size_t i = off + ((size_t)bx * 256 + threadIdx.x) * 4;
    float4 f = *(const float4*)(src + i);
    union { uint2 u2; ushort_t us[4]; } o;
    o.us[0] = f2b(f.x); o.us[1] = f2b(f.y); o.us[2] = f2b(f.z); o.us[3] = f2b(f.w);
    *(uint2*)(dst + i) = o.u2;
}

// ---------------------------------------------------------------------------
// Fused QKV projection GEMM: block tile 128x64 over N=3072 (Q|K|V).
// seg 0/1 -> bf16 store to qbb/kbb [t][1024]; seg 2 -> transposed store to
// vt [v_global 1024][t 2048].
// ---------------------------------------------------------------------------
__global__ __launch_bounds__(256) void gemm_qkv(
    const ushort_t* __restrict__ A0, const ushort_t* __restrict__ A1,
    const ushort_t* __restrict__ A2, const ushort_t* __restrict__ Wqkv,
    const float* __restrict__ b0, const float* __restrict__ b1,
    const float* __restrict__ b2,
    ushort_t* __restrict__ qbb, ushort_t* __restrict__ kbb,
    ushort_t* __restrict__ vt)
{
    __shared__ ushort_t As[128 * 64];
    __shared__ ushort_t Bs[64 * 64];
    const int tid = threadIdx.x;
    const int lane = tid & 63, wid = tid >> 6;
    const int quad = lane >> 4, l15 = lane & 15;
    const int wr = wid >> 1, wc = wid & 1;
    const int m0 = blockIdx.y * 128;
    const int n0 = blockIdx.x * 64;
    const int seg = n0 >> 10;
    const int nloc = n0 & 1023;
    const ushort_t* A = seg == 0 ? A0 : (seg == 1 ? A1 : A2);
    const float* bias = seg == 0 ? b0 : (seg == 1 ? b1 : b2);

    const f32x4 fz = {0.f, 0.f, 0.f, 0.f};
    f32x4 acc[4][2];
#pragma unroll
    for (int i = 0; i < 4; ++i) { acc[i][0] = fz; acc[i][1] = fz; }

    for (int k0 = 0; k0 < DMOD; k0 += 64) {
        __syncthreads();
#pragma unroll
        for (int i = 0; i < 4; ++i) {
            int c = i * 256 + tid, row = c >> 3, kcl = c & 7;
            gld16(A + (size_t)(m0 + row) * DMOD + k0 + (kcl ^ SW(row)) * 8, &As[c * 8]);
        }
#pragma unroll
        for (int i = 0; i < 2; ++i) {
            int c = i * 256 + tid, row = c >> 3, kcl = c & 7;
            gld16(Wqkv + (size_t)(n0 + row) * DMOD + k0 + (kcl ^ SW(row)) * 8, &Bs[c * 8]);
        }
        __syncthreads();
#pragma unroll
        for (int kc = 0; kc < 2; ++kc) {
            bf16x8 af[4], bfr[2];
#pragma unroll
            for (int mi = 0; mi < 4; ++mi) {
                int row = wr * 64 + mi * 16 + l15;
                af[mi] = *(const bf16x8*)&As[row * 64 + ((kc * 4 + quad) ^ SW(row)) * 8];
            }
#pragma unroll
            for (int ni = 0; ni < 2; ++ni) {
                int row = wc * 32 + ni * 16 + l15;
                bfr[ni] = *(const bf16x8*)&Bs[row * 64 + ((kc * 4 + quad) ^ SW(row)) * 8];
            }
#pragma unroll
            for (int mi = 0; mi < 4; ++mi)
#pragma unroll
                for (int ni = 0; ni < 2; ++ni)
                    acc[mi][ni] = __builtin_amdgcn_mfma_f32_16x16x32_bf16(
                        af[mi], bfr[ni], acc[mi][ni], 0, 0, 0);
        }
    }

    if (seg < 2) {
        ushort_t* C = seg == 0 ? qbb : kbb;
#pragma unroll
        for (int mi = 0; mi < 4; ++mi)
#pragma unroll
            for (int ni = 0; ni < 2; ++ni) {
                int gn = nloc + wc * 32 + ni * 16 + l15;
                float bv = bias[gn];
#pragma unroll
                for (int r = 0; r < 4; ++r) {
                    int gm = m0 + wr * 64 + mi * 16 + quad * 4 + r;
                    C[(size_t)gm * DMOD + gn] = f2b(acc[mi][ni][r] + bv);
                }
            }
    } else {
#pragma unroll
        for (int mi = 0; mi < 4; ++mi)
#pragma unroll
            for (int ni = 0; ni < 2; ++ni) {
                int gn = nloc + wc * 32 + ni * 16 + l15;   // v_global
                float bv = bias[gn];
                int gmb = m0 + wr * 64 + mi * 16 + quad * 4;
                union { uint2 u2; ushort_t us[4]; } o;
#pragma unroll
                for (int r = 0; r < 4; ++r) o.us[r] = f2b(acc[mi][ni][r] + bv);
                *(uint2*)&vt[(size_t)gn * S + gmb] = o.u2;
            }
    }
}

// ---------------------------------------------------------------------------
// Attention core v10: 256-row s-tile, 8 waves x 32 rows (2x 16-row subtiles),
// 16x16x32 fragments (conflict-free SW pattern, as v6). Each bk/bv LDS read
// feeds BOTH row-subtiles -> ~40% less LDS traffic per unit work; K/V staged
// half as often; barriers halve. 4 balanced chunks per (h,tile); pair
// bx/bx+256 gets tile i and 7-i -> every CU pair = 9 steps.
// Wave's hoisted Q rows == its P rows (wave-private) -> no extra barrier.
// ---------------------------------------------------------------------------
__global__ __launch_bounds__(512, 4) void attn_mfma(
    const ushort_t* __restrict__ qb, const ushort_t* __restrict__ kb,
    const ushort_t* __restrict__ vt, float* __restrict__ attn_raw,
    float* __restrict__ sumexp)
{
    __shared__ ushort_t QPs[256 * 64];     // Q staging, then P (wave-private rows)
    __shared__ ushort_t Ks[2][4096];
    __shared__ ushort_t Vs[2][4096];
    __shared__ float    sacc[512];

    const int bx = blockIdx.x;
    const int slot = bx >> 2, c = bx & 3;
    const int h = slot >> 3, iidx = slot & 7;
    const int si = (h < 8) ? iidx : 7 - iidx;   // pair-balance: i and 7-i
    const int csz = si + 1;                     // steps per chunk
    const int tbeg = c * csz, tend = tbeg + csz; // 4 chunks cover [0, 4si+4)
    const int s0 = si * 256;

    const int tid = threadIdx.x;
    const int lane = tid & 63, w = tid >> 6;
    const int quad = lane >> 4, l15 = lane & 15;
    const int sband = s0 + w * 32;     // wave's lowest s row
    const int nv = csz * 64;           // <= 512

    const ushort_t* qh = qb + h * 64;
    const ushort_t* kh = kb + h * 64;
    const ushort_t* vh = vt + (size_t)(h * 64) * S;

    // stage Q (256x64) + first K/V into buf 0
#pragma unroll
    for (int i = 0; i < 4; ++i) {
        int cc = i * 512 + tid, row = cc >> 3, kcl = cc & 7;
        gld16(qh + (size_t)(s0 + row) * DMOD + (kcl ^ SW(row)) * 8, &QPs[cc * 8]);
    }
    {
        int t0 = tbeg * 64;
        int row = tid >> 3, kcl = tid & 7;
        gld16(kh + (size_t)(t0 + row) * DMOD + (kcl ^ SW(row)) * 8, &Ks[0][tid * 8]);
        gld16(vh + (size_t)row * S + t0 + (kcl ^ SW(row)) * 8, &Vs[0][tid * 8]);
    }
    for (int i = tid; i < nv; i += 512) sacc[i] = 0.f;
    __syncthreads();

    // hoist step-invariant Q fragments: wave w reads rows [w*32, w*32+32),
    // exactly the P rows it later overwrites -> no extra barrier needed.
    bf16x8 aq[2][2];
#pragma unroll
    for (int rt = 0; rt < 2; ++rt) {
        int rq = w * 32 + rt * 16 + l15;
#pragma unroll
        for (int kc = 0; kc < 2; ++kc)
            aq[rt][kc] = *(const bf16x8*)&QPs[rq * 64 + ((kc * 4 + quad) ^ SW(rq)) * 8];
    }

    const f32x4 fz = {0.f, 0.f, 0.f, 0.f};
    f32x4 oacc[2][4];
#pragma unroll
    for (int rt = 0; rt < 2; ++rt)
#pragma unroll
        for (int ni = 0; ni < 4; ++ni) oacc[rt][ni] = fz;
    bool any_live = false;

    for (int it = tbeg; it < tend; ++it) {
        const int p = (it - tbeg) & 1;
        const int t0 = it * 64;
        // prefetch next K/V into the other buffer (overlaps this step's compute)
        if (it + 1 < tend) {
            int t1 = t0 + 64;
            int row = tid >> 3, kcl = tid & 7;
            gld16(kh + (size_t)(t1 + row) * DMOD + (kcl ^ SW(row)) * 8, &Ks[1 - p][tid * 8]);
            gld16(vh + (size_t)row * S + t1 + (kcl ^ SW(row)) * 8, &Vs[1 - p][tid * 8]);
        }

        if (t0 < sband + 32) {   // not fully masked for this wave's 32 rows
            any_live = true;
            // X = Q K^T  (two 16-row subtiles share each bk read)
            f32x4 xf[2][4];
#pragma unroll
            for (int rt = 0; rt < 2; ++rt)
#pragma unroll
                for (int ti = 0; ti < 4; ++ti) xf[rt][ti] = fz;
#pragma unroll
            for (int kc = 0; kc < 2; ++kc) {
#pragma unroll
                for (int ti = 0; ti < 4; ++ti) {
                    int rk = ti * 16 + l15;
                    bf16x8 bk = *(const bf16x8*)&Ks[p][rk * 64 + ((kc * 4 + quad) ^ SW(rk)) * 8];
#pragma unroll
                    for (int rt = 0; rt < 2; ++rt)
                        xf[rt][ti] = __builtin_amdgcn_mfma_f32_16x16x32_bf16(
                            aq[rt][kc], bk, xf[rt][ti], 0, 0, 0);
                }
            }

            // scale, mask, exp column sums -> LDS, P -> wave-private LDS
#pragma unroll
            for (int rt = 0; rt < 2; ++rt) {
                const int sb_rt = sband + rt * 16;
                const bool clean = (t0 + 63 <= sb_rt);   // wave-uniform
                const int s_q = sb_rt + quad * 4;
#pragma unroll
                for (int ti = 0; ti < 4; ++ti) {
                    int t_g = t0 + ti * 16 + l15;
                    float es = 0.f;
                    if (clean) {
#pragma unroll
                        for (int r = 0; r < 4; ++r) {
                            float xv = xf[rt][ti][r] * 0.125f;
                            es += __expf(xv);
                            xf[rt][ti][r] = xv;
                        }
                    } else {
#pragma unroll
                        for (int r = 0; r < 4; ++r) {
                            float xv = xf[rt][ti][r] * 0.125f;
                            bool live = (s_q + r >= t_g);
                            xv = live ? xv : 0.f;
                            es += live ? __expf(xv) : 0.f;
                            xf[rt][ti][r] = xv;
                        }
                    }
                    es += __shfl_xor(es, 16, 64);
                    es += __shfl_xor(es, 32, 64);
                    if (quad == 0) atomicAdd(&sacc[(it - tbeg) * 64 + ti * 16 + l15], es);
#pragma unroll
                    for (int r = 0; r < 4; ++r) {
                        int sl = w * 32 + rt * 16 + quad * 4 + r;
                        int tc = ti * 16 + l15;
                        QPs[sl * 64 + ((tc >> 3) ^ SW(sl)) * 8 + (tc & 7)] = f2b_fast(xf[rt][ti][r]);
                    }
                }
            }

            // O += P V   (bv shared across both row-subtiles)
#pragma unroll
            for (int kc = 0; kc < 2; ++kc) {
                bf16x8 ap[2];
#pragma unroll
                for (int rt = 0; rt < 2; ++rt) {
                    int rp = w * 32 + rt * 16 + l15;
                    ap[rt] = *(const bf16x8*)&QPs[rp * 64 + ((kc * 4 + quad) ^ SW(rp)) * 8];
                }
#pragma unroll
                for (int ni = 0; ni < 4; ++ni) {
                    int rv = ni * 16 + l15;
                    bf16x8 bv = *(const bf16x8*)&Vs[p][rv * 64 + ((kc * 4 + quad) ^ SW(rv)) * 8];
#pragma unroll
                    for (int rt = 0; rt < 2; ++rt)
                        oacc[rt][ni] = __builtin_amdgcn_mfma_f32_16x16x32_bf16(
                            ap[rt], bv, oacc[rt][ni], 0, 0, 0);
                }
            }
        }
        __syncthreads();   // all waves done with buf p; next iter stages into it
    }

    // exp-sum burst: one global atomic per covered t
    for (int i = tid; i < nv; i += 512)
        atomicAdd(&sumexp[h * S + tbeg * 64 + i], sacc[i]);
    // O accumulate (4 chunks per (h,tile) sum into zeroed attn_raw)
    if (any_live) {
#pragma unroll
        for (int rt = 0; rt < 2; ++rt)
#pragma unroll
            for (int ni = 0; ni < 4; ++ni)
#pragma unroll
                for (int r = 0; r < 4; ++r) {
                    int s_g = s0 + w * 32 + rt * 16 + quad * 4 + r;
                    atomicAdd(&attn_raw[(size_t)s_g * DMOD + h * 64 + ni * 16 + l15],
                              oacc[rt][ni][r]);
                }
    }
}

// ---------------------------------------------------------------------------
// corr[r=h*64+j] = sum_t log(sumexp[h,t]) * vt[r][t].
// One block per 16 rows (grid 64); log(sumexp) computed ONCE per block into
// LDS with fast __logf, then LDS-resident dot products.
// ---------------------------------------------------------------------------
__global__ __launch_bounds__(256) void corr_kernel(
    const float* __restrict__ sumexp, const ushort_t* __restrict__ vt,
    float* __restrict__ corr)
{
    __shared__ float ls[S];
    const int h = blockIdx.x >> 2;
    const int r0 = blockIdx.x * 16;
    const int tid = threadIdx.x;
    for (int t = tid; t < S; t += 256)
        ls[t] = __logf(sumexp[h * S + t]);
    __syncthreads();
    const int w = tid >> 6, lane = tid & 63;
#pragma unroll
    for (int rr = 0; rr < 4; ++rr) {
        int r = r0 + w * 4 + rr;
        float acc = 0.f;
#pragma unroll
        for (int i = 0; i < 4; ++i) {
            int t = i * 512 + lane * 8;
            bf16x8 vv = *(const bf16x8*)&vt[(size_t)r * S + t];
#pragma unroll
            for (int j = 0; j < 8; ++j)
                acc += ls[t + j] * b2f((ushort_t)vv[j]);
        }
#pragma unroll
        for (int d = 1; d < 64; d <<= 1) acc += __shfl_xor(acc, d, 64);
        if (lane == 0) corr[r] = acc;
    }
}

// ---------------------------------------------------------------------------
__global__ __launch_bounds__(256) void convert_Z(
    const float* __restrict__ attn_raw, const float* __restrict__ corr,
    ushort_t* __restrict__ Zb)
{
    size_t i = ((size_t)blockIdx.x * 256 + threadIdx.x) * 4;
    float4 f = *(const float4*)(attn_raw + i);
    int c = (int)(i & (DMOD - 1));
    union { uint2 u2; ushort_t us[4]; } o;
    o.us[0] = f2b(f.x - corr[c]);
    o.us[1] = f2b(f.y - corr[c + 1]);
    o.us[2] = f2b(f.z - corr[c + 2]);
    o.us[3] = f2b(f.w - corr[c + 3]);
    *(uint2*)(Zb + i) = o.u2;
}

// ---------------------------------------------------------------------------
// Output GEMM, split-K=2, atomic fp32 epilogue (d_out zeroed by prep_all).
// ---------------------------------------------------------------------------
__global__ __launch_bounds__(256) void gemm_out(
    const ushort_t* __restrict__ A, const ushort_t* __restrict__ W,
    const float* __restrict__ bias, float* __restrict__ C)
{
    __shared__ ushort_t As[128 * 64];
    __shared__ ushort_t Bs[64 * 64];
    const int tid = threadIdx.x;
    const int lane = tid & 63, wid = tid >> 6;
    const int quad = lane >> 4, l15 = lane & 15;
    const int wr = wid >> 1, wc = wid & 1;
    const int m0 = blockIdx.y * 128, n0 = blockIdx.x * 64;
    const int kbeg = blockIdx.z * 512, kend = kbeg + 512;

    const f32x4 fz = {0.f, 0.f, 0.f, 0.f};
    f32x4 acc[4][2];
#pragma unroll
    for (int i = 0; i < 4; ++i) { acc[i][0] = fz; acc[i][1] = fz; }

    for (int k0 = kbeg; k0 < kend; k0 += 64) {
        __syncthreads();
#pragma unroll
        for (int i = 0; i < 4; ++i) {
            int c = i * 256 + tid, row = c >> 3, kcl = c & 7;
            gld16(A + (size_t)(m0 + row) * DMOD + k0 + (kcl ^ SW(row)) * 8, &As[c * 8]);
        }
#pragma unroll
        for (int i = 0; i < 2; ++i) {
            int c = i * 256 + tid, row = c >> 3, kcl = c & 7;
            gld16(W + (size_t)(n0 + row) * DMOD + k0 + (kcl ^ SW(row)) * 8, &Bs[c * 8]);
        }
        __syncthreads();
#pragma unroll
        for (int kc = 0; kc < 2; ++kc) {
            bf16x8 af[4], bfr[2];
#pragma unroll
            for (int mi = 0; mi < 4; ++mi) {
                int row = wr * 64 + mi * 16 + l15;
                af[mi] = *(const bf16x8*)&As[row * 64 + ((kc * 4 + quad) ^ SW(row)) * 8];
            }
#pragma unroll
            for (int ni = 0; ni < 2; ++ni) {
                int row = wc * 32 + ni * 16 + l15;
                bfr[ni] = *(const bf16x8*)&Bs[row * 64 + ((kc * 4 + quad) ^ SW(row)) * 8];
            }
#pragma unroll
            for (int mi = 0; mi < 4; ++mi)
#pragma unroll
                for (int ni = 0; ni < 2; ++ni)
                    acc[mi][ni] = __builtin_amdgcn_mfma_f32_16x16x32_bf16(
                        af[mi], bfr[ni], acc[mi][ni], 0, 0, 0);
        }
    }
#pragma unroll
    for (int mi = 0; mi < 4; ++mi)
#pragma unroll
        for (int ni = 0; ni < 2; ++ni) {
            int gn = n0 + wc * 32 + ni * 16 + l15;
            float bv = (kbeg == 0) ? bias[gn] : 0.f;
#pragma unroll
            for (int r = 0; r < 4; ++r) {
                int gm = m0 + wr * 64 + mi * 16 + quad * 4 + r;
                atomicAdd(&C[(size_t)gm * DMOD + gn], acc[mi][ni][r] + bv);
            }
        }
}

// ---------------------------------------------------------------------------
extern "C" void kernel_launch(void* const* d_in, const int* in_sizes, int n_in,
                              void* d_out, int out_size, void* d_ws, size_t ws_size,
                              hipStream_t stream) {
    const float* Qin = (const float*)d_in[0];
    const float* Kin = (const float*)d_in[1];
    const float* Vin = (const float*)d_in[2];
    const float* WQw = (const float*)d_in[3];
    const float* WQb = (const float*)d_in[4];
    const float* WKw = (const float*)d_in[5];
    const float* WKb = (const float*)d_in[6];
    const float* WVw = (const float*)d_in[7];
    const float* WVb = (const float*)d_in[8];
    const float* WOw = (const float*)d_in[9];
    const float* WOb = (const float*)d_in[10];

    float* ws = (float*)d_ws;
    const size_t M1 = (size_t)1 << 20;
    ushort_t* qbb  = (ushort_t*)(ws);                 // [2048][1024] bf16   0-4MB
    ushort_t* kbb  = (ushort_t*)(ws + M1);            //                    4-8MB
    ushort_t* vt   = (ushort_t*)(ws + 2 * M1);        // [1024 v][2048 t]   8-12MB
    ushort_t* wqkv = (ushort_t*)(ws + 3 * M1);        // [3072][1024]      12-18MB
    ushort_t* wob  = (ushort_t*)(ws + 4 * M1 + M1 / 2); //                 18-20MB
    ushort_t* Qbin = (ushort_t*)(ws + 5 * M1);        // 20-24MB, reused as Zb
    ushort_t* Kbin = (ushort_t*)(ws + 6 * M1);        // 24-28MB
    ushort_t* Vbin = (ushort_t*)(ws + 7 * M1);        // 28-32MB
    float* sumexp   = ws + 8 * M1;                    // 32MB, 128KB
    float* corr     = ws + 8 * M1 + H * S;            // +4KB
    float* attn_raw = ws + 9 * M1;                    // 36-44MB (no aliasing)
    ushort_t* Zb    = (ushort_t*)(ws + 5 * M1);

    prep_all<<<dim3(1024, 15), 256, 0, stream>>>(
        Qin, Kin, Vin, WQw, WKw, WVw, WOw,
        Qbin, Kbin, Vbin,
        wqkv, wqkv + (size_t)1024 * 1024, wqkv + (size_t)2 * 1024 * 1024, wob,
        attn_raw, (float*)d_out, sumexp, corr);

    gemm_qkv<<<dim3(48, 16), 256, 0, stream>>>(
        Qbin, Kbin, Vbin, wqkv, WQb, WKb, WVb, qbb, kbb, vt);

    attn_mfma<<<512, 512, 0, stream>>>(qbb, kbb, vt, attn_raw, sumexp);

    corr_kernel<<<64, 256, 0, stream>>>(sumexp, vt, corr);
    convert_Z<<<2048, 256, 0, stream>>>(attn_raw, corr, Zb);

    gemm_out<<<dim3(16, 16, 2), 256, 0, stream>>>(Zb, wob, WOb, (float*)d_out);
}

// Round 11
// 183.948 us; speedup vs baseline: 1.2379x; 1.2379x over previous
//
#include <hip/hip_runtime.h>
#include <math.h>
#include <stdint.h>

#define S 2048
#define DMOD 1024
#define H 16

typedef unsigned short ushort_t;
typedef short bf16x8 __attribute__((ext_vector_type(8)));
typedef float f32x4 __attribute__((ext_vector_type(4)));

// chunk swizzle: rows 1..7 apart and 8 apart land on different chunk columns
#define SW(r) ((((r) & 7)) ^ ((((r) >> 3) & 3) << 1))

__device__ __forceinline__ ushort_t f2b(float f) {
    union { float f; unsigned u; } x; x.f = f;
    return (ushort_t)((x.u + 0x7FFFu + ((x.u >> 16) & 1u)) >> 16);
}
// round-half-up bf16 (2 ops); differs from RNE only on exact-tie mantissas
__device__ __forceinline__ ushort_t f2b_fast(float f) {
    union { float f; unsigned u; } x; x.f = f;
    return (ushort_t)((x.u + 0x8000u) >> 16);
}
__device__ __forceinline__ float b2f(ushort_t b) {
    union { unsigned u; float f; } x; x.u = ((unsigned)b) << 16;
    return x.f;
}
__device__ __forceinline__ void gld16(const ushort_t* g, ushort_t* l) {
    __builtin_amdgcn_global_load_lds(
        (const __attribute__((address_space(1))) unsigned int*)g,
        (__attribute__((address_space(3))) unsigned int*)l, 16, 0, 0);
}

// ---------------------------------------------------------------------------
// prep_all = convert + init merged. All destination regions are DISJOINT
// (attn_raw lives at ws+9M1, past every bf16 buffer).
// ---------------------------------------------------------------------------
__global__ __launch_bounds__(256) void prep_all(
    const float* q, const float* k, const float* v,
    const float* wq, const float* wk, const float* wv, const float* wo,
    ushort_t* qo, ushort_t* ko, ushort_t* vo,
    ushort_t* wqo, ushort_t* wko, ushort_t* wvo, ushort_t* woo,
    float* __restrict__ attn_raw, float* __restrict__ out,
    float* __restrict__ sumexp, float* __restrict__ corr)
{
    const int seg = blockIdx.y;
    const int bx = blockIdx.x;
    if (seg >= 10) {
        const float4 z4 = {0.f, 0.f, 0.f, 0.f};
        if (seg < 12) {
            *(float4*)(attn_raw + (((size_t)(seg - 10) * 1024 + bx) * 256 + threadIdx.x) * 4) = z4;
        } else if (seg < 14) {
            *(float4*)(out + (((size_t)(seg - 12) * 1024 + bx) * 256 + threadIdx.x) * 4) = z4;
        } else if (bx < 32) {
            int e = (bx * 256 + threadIdx.x) * 4;
            float4 vv = {(float)(e & 2047), (float)((e + 1) & 2047),
                         (float)((e + 2) & 2047), (float)((e + 3) & 2047)};
            *(float4*)(sumexp + e) = vv;
        } else if (bx == 32) {
            *(float4*)(corr + threadIdx.x * 4) = z4;
        }
        return;
    }
    const float* src; ushort_t* dst; size_t off = 0;
    const size_t M1 = (size_t)1 << 20;
    if (seg < 2)       { src = q;  dst = qo;  off = (size_t)seg * M1; }
    else if (seg < 4)  { src = k;  dst = ko;  off = (size_t)(seg - 2) * M1; }
    else if (seg < 6)  { src = v;  dst = vo;  off = (size_t)(seg - 4) * M1; }
    else if (seg == 6) { src = wq; dst = wqo; }
    else if (seg == 7) { src = wk; dst = wko; }
    else if (seg == 8) { src = wv; dst = wvo; }
    else               { src = wo; dst = woo; }
    size_t i = off + ((size_t)bx * 256 + threadIdx.x) * 4;
    float4 f = *(const float4*)(src + i);
    union { uint2 u2; ushort_t us[4]; } o;
    o.us[0] = f2b(f.x); o.us[1] = f2b(f.y); o.us[2] = f2b(f.z); o.us[3] = f2b(f.w);
    *(uint2*)(dst + i) = o.u2;
}

// ---------------------------------------------------------------------------
// Fused QKV projection GEMM: block tile 128x64 over N=3072 (Q|K|V).
// seg 0/1 -> bf16 store to qbb/kbb [t][1024]; seg 2 -> transposed store to
// vt [v_global 1024][t 2048].
// ---------------------------------------------------------------------------
__global__ __launch_bounds__(256) void gemm_qkv(
    const ushort_t* __restrict__ A0, const ushort_t* __restrict__ A1,
    const ushort_t* __restrict__ A2, const ushort_t* __restrict__ Wqkv,
    const float* __restrict__ b0, const float* __restrict__ b1,
    const float* __restrict__ b2,
    ushort_t* __restrict__ qbb, ushort_t* __restrict__ kbb,
    ushort_t* __restrict__ vt)
{
    __shared__ ushort_t As[128 * 64];
    __shared__ ushort_t Bs[64 * 64];
    const int tid = threadIdx.x;
    const int lane = tid & 63, wid = tid >> 6;
    const int quad = lane >> 4, l15 = lane & 15;
    const int wr = wid >> 1, wc = wid & 1;
    const int m0 = blockIdx.y * 128;
    const int n0 = blockIdx.x * 64;
    const int seg = n0 >> 10;
    const int nloc = n0 & 1023;
    const ushort_t* A = seg == 0 ? A0 : (seg == 1 ? A1 : A2);
    const float* bias = seg == 0 ? b0 : (seg == 1 ? b1 : b2);

    const f32x4 fz = {0.f, 0.f, 0.f, 0.f};
    f32x4 acc[4][2];
#pragma unroll
    for (int i = 0; i < 4; ++i) { acc[i][0] = fz; acc[i][1] = fz; }

    for (int k0 = 0; k0 < DMOD; k0 += 64) {
        __syncthreads();
#pragma unroll
        for (int i = 0; i < 4; ++i) {
            int c = i * 256 + tid, row = c >> 3, kcl = c & 7;
            gld16(A + (size_t)(m0 + row) * DMOD + k0 + (kcl ^ SW(row)) * 8, &As[c * 8]);
        }
#pragma unroll
        for (int i = 0; i < 2; ++i) {
            int c = i * 256 + tid, row = c >> 3, kcl = c & 7;
            gld16(Wqkv + (size_t)(n0 + row) * DMOD + k0 + (kcl ^ SW(row)) * 8, &Bs[c * 8]);
        }
        __syncthreads();
#pragma unroll
        for (int kc = 0; kc < 2; ++kc) {
            bf16x8 af[4], bfr[2];
#pragma unroll
            for (int mi = 0; mi < 4; ++mi) {
                int row = wr * 64 + mi * 16 + l15;
                af[mi] = *(const bf16x8*)&As[row * 64 + ((kc * 4 + quad) ^ SW(row)) * 8];
            }
#pragma unroll
            for (int ni = 0; ni < 2; ++ni) {
                int row = wc * 32 + ni * 16 + l15;
                bfr[ni] = *(const bf16x8*)&Bs[row * 64 + ((kc * 4 + quad) ^ SW(row)) * 8];
            }
#pragma unroll
            for (int mi = 0; mi < 4; ++mi)
#pragma unroll
                for (int ni = 0; ni < 2; ++ni)
                    acc[mi][ni] = __builtin_amdgcn_mfma_f32_16x16x32_bf16(
                        af[mi], bfr[ni], acc[mi][ni], 0, 0, 0);
        }
    }

    if (seg < 2) {
        ushort_t* C = seg == 0 ? qbb : kbb;
#pragma unroll
        for (int mi = 0; mi < 4; ++mi)
#pragma unroll
            for (int ni = 0; ni < 2; ++ni) {
                int gn = nloc + wc * 32 + ni * 16 + l15;
                float bv = bias[gn];
#pragma unroll
                for (int r = 0; r < 4; ++r) {
                    int gm = m0 + wr * 64 + mi * 16 + quad * 4 + r;
                    C[(size_t)gm * DMOD + gn] = f2b(acc[mi][ni][r] + bv);
                }
            }
    } else {
#pragma unroll
        for (int mi = 0; mi < 4; ++mi)
#pragma unroll
            for (int ni = 0; ni < 2; ++ni) {
                int gn = nloc + wc * 32 + ni * 16 + l15;   // v_global
                float bv = bias[gn];
                int gmb = m0 + wr * 64 + mi * 16 + quad * 4;
                union { uint2 u2; ushort_t us[4]; } o;
#pragma unroll
                for (int r = 0; r < 4; ++r) o.us[r] = f2b(acc[mi][ni][r] + bv);
                *(uint2*)&vt[(size_t)gn * S + gmb] = o.u2;
            }
    }
}

// ---------------------------------------------------------------------------
// Attention core v6 (reverted; best measured): 3-way balanced split,
// plain __syncthreads, 16x16x32 fragments, 128-row tile, 8 waves x 16 rows.
// ---------------------------------------------------------------------------
__global__ __launch_bounds__(512, 4) void attn_mfma(
    const ushort_t* __restrict__ qb, const ushort_t* __restrict__ kb,
    const ushort_t* __restrict__ vt, float* __restrict__ attn_raw,
    float* __restrict__ sumexp)
{
    __shared__ ushort_t QPs[128 * 64];     // Q staging, then P (wave-private rows)
    __shared__ ushort_t Ks[2][4096];
    __shared__ ushort_t Vs[2][4096];
    __shared__ float    sacc[1024];

    const int slot = blockIdx.x;
    const int h = slot >> 4, u = slot & 15;
    const int rnd = blockIdx.y;
    int si, tbeg, tend;
    if (rnd == 0) { si = 15 - u; tbeg = 0; tend = si + 1; }
    else {
        si = u;
        const int b0 = u + 1, Bc = (u + 2) >> 1;
        if (rnd == 1) { tbeg = b0; tend = b0 + Bc; }
        else          { tbeg = b0 + Bc; tend = 2 * u + 2; }
    }
    if (tbeg >= tend) return;          // empty chunk (u=0, round 2)
    const int s0 = si * 128;

    const int tid = threadIdx.x;
    const int lane = tid & 63, w = tid >> 6;
    const int quad = lane >> 4, l15 = lane & 15;
    const int sband = s0 + w * 16;     // wave's lowest s row
    const int nv = (tend - tbeg) * 64;

    const ushort_t* qh = qb + h * 64;
    const ushort_t* kh = kb + h * 64;
    const ushort_t* vh = vt + (size_t)(h * 64) * S;

    // stage Q (128x64) + first K/V into buf 0
#pragma unroll
    for (int i = 0; i < 2; ++i) {
        int c = i * 512 + tid, row = c >> 3, kcl = c & 7;
        gld16(qh + (size_t)(s0 + row) * DMOD + (kcl ^ SW(row)) * 8, &QPs[c * 8]);
    }
    {
        int t0 = tbeg * 64;
        int row = tid >> 3, kcl = tid & 7;
        gld16(kh + (size_t)(t0 + row) * DMOD + (kcl ^ SW(row)) * 8, &Ks[0][tid * 8]);
        gld16(vh + (size_t)row * S + t0 + (kcl ^ SW(row)) * 8, &Vs[0][tid * 8]);
    }
    for (int i = tid; i < nv; i += 512) sacc[i] = 0.f;
    __syncthreads();

    // hoist step-invariant Q fragments (wave w reads only rows [w*16, w*16+16),
    // which are exactly the P rows it later overwrites -> no extra barrier)
    bf16x8 aq[2];
    {
        int rq = w * 16 + l15;
#pragma unroll
        for (int kc = 0; kc < 2; ++kc)
            aq[kc] = *(const bf16x8*)&QPs[rq * 64 + ((kc * 4 + quad) ^ SW(rq)) * 8];
    }

    const f32x4 fz = {0.f, 0.f, 0.f, 0.f};
    f32x4 oacc[4];
#pragma unroll
    for (int ni = 0; ni < 4; ++ni) oacc[ni] = fz;
    bool any_live = false;

    for (int it = tbeg; it < tend; ++it) {
        const int p = (it - tbeg) & 1;
        const int t0 = it * 64;
        // prefetch next K/V into the other buffer (overlaps this step's compute)
        if (it + 1 < tend) {
            int t1 = t0 + 64;
            int row = tid >> 3, kcl = tid & 7;
            gld16(kh + (size_t)(t1 + row) * DMOD + (kcl ^ SW(row)) * 8, &Ks[1 - p][tid * 8]);
            gld16(vh + (size_t)row * S + t1 + (kcl ^ SW(row)) * 8, &Vs[1 - p][tid * 8]);
        }

        if (t0 < sband + 16) {   // not fully masked for this wave band
            any_live = true;
            // X = Q K^T
            f32x4 xf[4];
#pragma unroll
            for (int ti = 0; ti < 4; ++ti) xf[ti] = fz;
#pragma unroll
            for (int kc = 0; kc < 2; ++kc) {
#pragma unroll
                for (int ti = 0; ti < 4; ++ti) {
                    int rk = ti * 16 + l15;
                    bf16x8 bk = *(const bf16x8*)&Ks[p][rk * 64 + ((kc * 4 + quad) ^ SW(rk)) * 8];
                    xf[ti] = __builtin_amdgcn_mfma_f32_16x16x32_bf16(aq[kc], bk, xf[ti], 0, 0, 0);
                }
            }

            // scale, mask, exp column sums -> LDS, P -> wave-private LDS
            const bool clean = (t0 + 63 <= sband);   // wave-uniform
            const int s_q = sband + quad * 4;
#pragma unroll
            for (int ti = 0; ti < 4; ++ti) {
                int t_g = t0 + ti * 16 + l15;
                float es = 0.f;
                if (clean) {
#pragma unroll
                    for (int r = 0; r < 4; ++r) {
                        float xv = xf[ti][r] * 0.125f;
                        es += __expf(xv);
                        xf[ti][r] = xv;
                    }
                } else {
#pragma unroll
                    for (int r = 0; r < 4; ++r) {
                        float xv = xf[ti][r] * 0.125f;
                        bool live = (s_q + r >= t_g);
                        xv = live ? xv : 0.f;
                        es += live ? __expf(xv) : 0.f;
                        xf[ti][r] = xv;
                    }
                }
                es += __shfl_xor(es, 16, 64);
                es += __shfl_xor(es, 32, 64);
                if (quad == 0) atomicAdd(&sacc[(it - tbeg) * 64 + ti * 16 + l15], es);
#pragma unroll
                for (int r = 0; r < 4; ++r) {
                    int sl = w * 16 + quad * 4 + r;
                    int tc = ti * 16 + l15;
                    QPs[sl * 64 + ((tc >> 3) ^ SW(sl)) * 8 + (tc & 7)] = f2b_fast(xf[ti][r]);
                }
            }

            // O += P V   (reads only this wave's P rows)
#pragma unroll
            for (int kc = 0; kc < 2; ++kc) {
                int rp = w * 16 + l15;
                bf16x8 ap = *(const bf16x8*)&QPs[rp * 64 + ((kc * 4 + quad) ^ SW(rp)) * 8];
#pragma unroll
                for (int ni = 0; ni < 4; ++ni) {
                    int rv = ni * 16 + l15;
                    bf16x8 bv = *(const bf16x8*)&Vs[p][rv * 64 + ((kc * 4 + quad) ^ SW(rv)) * 8];
                    oacc[ni] = __builtin_amdgcn_mfma_f32_16x16x32_bf16(ap, bv, oacc[ni], 0, 0, 0);
                }
            }
        }
        __syncthreads();   // all waves done with buf p; next iter stages into it
    }

    // exp-sum burst: one global atomic per covered t
    for (int i = tid; i < nv; i += 512)
        atomicAdd(&sumexp[h * S + tbeg * 64 + i], sacc[i]);
    // O accumulate (chunks per (h,si) sum into zeroed attn_raw)
    if (any_live) {
#pragma unroll
        for (int ni = 0; ni < 4; ++ni)
#pragma unroll
            for (int r = 0; r < 4; ++r) {
                int s_g = s0 + w * 16 + quad * 4 + r;
                atomicAdd(&attn_raw[(size_t)s_g * DMOD + h * 64 + ni * 16 + l15],
                          oacc[ni][r]);
            }
    }
}

// ---------------------------------------------------------------------------
// corr[r=h*64+j] = sum_t log(sumexp[h,t]) * vt[r][t].
// One block per 16 rows (grid 64); log(sumexp) computed ONCE per block into
// LDS with fast __logf, then LDS-resident dot products.
// ---------------------------------------------------------------------------
__global__ __launch_bounds__(256) void corr_kernel(
    const float* __restrict__ sumexp, const ushort_t* __restrict__ vt,
    float* __restrict__ corr)
{
    __shared__ float ls[S];
    const int h = blockIdx.x >> 2;
    const int r0 = blockIdx.x * 16;
    const int tid = threadIdx.x;
    for (int t = tid; t < S; t += 256)
        ls[t] = __logf(sumexp[h * S + t]);
    __syncthreads();
    const int w = tid >> 6, lane = tid & 63;
#pragma unroll
    for (int rr = 0; rr < 4; ++rr) {
        int r = r0 + w * 4 + rr;
        float acc = 0.f;
#pragma unroll
        for (int i = 0; i < 4; ++i) {
            int t = i * 512 + lane * 8;
            bf16x8 vv = *(const bf16x8*)&vt[(size_t)r * S + t];
#pragma unroll
            for (int j = 0; j < 8; ++j)
                acc += ls[t + j] * b2f((ushort_t)vv[j]);
        }
#pragma unroll
        for (int d = 1; d < 64; d <<= 1) acc += __shfl_xor(acc, d, 64);
        if (lane == 0) corr[r] = acc;
    }
}

// ---------------------------------------------------------------------------
__global__ __launch_bounds__(256) void convert_Z(
    const float* __restrict__ attn_raw, const float* __restrict__ corr,
    ushort_t* __restrict__ Zb)
{
    size_t i = ((size_t)blockIdx.x * 256 + threadIdx.x) * 4;
    float4 f = *(const float4*)(attn_raw + i);
    int c = (int)(i & (DMOD - 1));
    union { uint2 u2; ushort_t us[4]; } o;
    o.us[0] = f2b(f.x - corr[c]);
    o.us[1] = f2b(f.y - corr[c + 1]);
    o.us[2] = f2b(f.z - corr[c + 2]);
    o.us[3] = f2b(f.w - corr[c + 3]);
    *(uint2*)(Zb + i) = o.u2;
}

// ---------------------------------------------------------------------------
// Output GEMM v2: full K=1024 per block (split-K=1), 256 blocks = 1/CU,
// plain f32 stores with bias (no atomics, no dependence on zeroed d_out).
// ---------------------------------------------------------------------------
__global__ __launch_bounds__(256) void gemm_out(
    const ushort_t* __restrict__ A, const ushort_t* __restrict__ W,
    const float* __restrict__ bias, float* __restrict__ C)
{
    __shared__ ushort_t As[128 * 64];
    __shared__ ushort_t Bs[64 * 64];
    const int tid = threadIdx.x;
    const int lane = tid & 63, wid = tid >> 6;
    const int quad = lane >> 4, l15 = lane & 15;
    const int wr = wid >> 1, wc = wid & 1;
    const int m0 = blockIdx.y * 128, n0 = blockIdx.x * 64;

    const f32x4 fz = {0.f, 0.f, 0.f, 0.f};
    f32x4 acc[4][2];
#pragma unroll
    for (int i = 0; i < 4; ++i) { acc[i][0] = fz; acc[i][1] = fz; }

    for (int k0 = 0; k0 < DMOD; k0 += 64) {
        __syncthreads();
#pragma unroll
        for (int i = 0; i < 4; ++i) {
            int c = i * 256 + tid, row = c >> 3, kcl = c & 7;
            gld16(A + (size_t)(m0 + row) * DMOD + k0 + (kcl ^ SW(row)) * 8, &As[c * 8]);
        }
#pragma unroll
        for (int i = 0; i < 2; ++i) {
            int c = i * 256 + tid, row = c >> 3, kcl = c & 7;
            gld16(W + (size_t)(n0 + row) * DMOD + k0 + (kcl ^ SW(row)) * 8, &Bs[c * 8]);
        }
        __syncthreads();
#pragma unroll
        for (int kc = 0; kc < 2; ++kc) {
            bf16x8 af[4], bfr[2];
#pragma unroll
            for (int mi = 0; mi < 4; ++mi) {
                int row = wr * 64 + mi * 16 + l15;
                af[mi] = *(const bf16x8*)&As[row * 64 + ((kc * 4 + quad) ^ SW(row)) * 8];
            }
#pragma unroll
            for (int ni = 0; ni < 2; ++ni) {
                int row = wc * 32 + ni * 16 + l15;
                bfr[ni] = *(const bf16x8*)&Bs[row * 64 + ((kc * 4 + quad) ^ SW(row)) * 8];
            }
#pragma unroll
            for (int mi = 0; mi < 4; ++mi)
#pragma unroll
                for (int ni = 0; ni < 2; ++ni)
                    acc[mi][ni] = __builtin_amdgcn_mfma_f32_16x16x32_bf16(
                        af[mi], bfr[ni], acc[mi][ni], 0, 0, 0);
        }
    }
#pragma unroll
    for (int mi = 0; mi < 4; ++mi)
#pragma unroll
        for (int ni = 0; ni < 2; ++ni) {
            int gn = n0 + wc * 32 + ni * 16 + l15;
            float bv = bias[gn];
#pragma unroll
            for (int r = 0; r < 4; ++r) {
                int gm = m0 + wr * 64 + mi * 16 + quad * 4 + r;
                C[(size_t)gm * DMOD + gn] = acc[mi][ni][r] + bv;
            }
        }
}

// ---------------------------------------------------------------------------
extern "C" void kernel_launch(void* const* d_in, const int* in_sizes, int n_in,
                              void* d_out, int out_size, void* d_ws, size_t ws_size,
                              hipStream_t stream) {
    const float* Qin = (const float*)d_in[0];
    const float* Kin = (const float*)d_in[1];
    const float* Vin = (const float*)d_in[2];
    const float* WQw = (const float*)d_in[3];
    const float* WQb = (const float*)d_in[4];
    const float* WKw = (const float*)d_in[5];
    const float* WKb = (const float*)d_in[6];
    const float* WVw = (const float*)d_in[7];
    const float* WVb = (const float*)d_in[8];
    const float* WOw = (const float*)d_in[9];
    const float* WOb = (const float*)d_in[10];

    float* ws = (float*)d_ws;
    const size_t M1 = (size_t)1 << 20;
    ushort_t* qbb  = (ushort_t*)(ws);                 // [2048][1024] bf16   0-4MB
    ushort_t* kbb  = (ushort_t*)(ws + M1);            //                    4-8MB
    ushort_t* vt   = (ushort_t*)(ws + 2 * M1);        // [1024 v][2048 t]   8-12MB
    ushort_t* wqkv = (ushort_t*)(ws + 3 * M1);        // [3072][1024]      12-18MB
    ushort_t* wob  = (ushort_t*)(ws + 4 * M1 + M1 / 2); //                 18-20MB
    ushort_t* Qbin = (ushort_t*)(ws + 5 * M1);        // 20-24MB, reused as Zb
    ushort_t* Kbin = (ushort_t*)(ws + 6 * M1);        // 24-28MB
    ushort_t* Vbin = (ushort_t*)(ws + 7 * M1);        // 28-32MB
    float* sumexp   = ws + 8 * M1;                    // 32MB, 128KB
    float* corr     = ws + 8 * M1 + H * S;            // +4KB
    float* attn_raw = ws + 9 * M1;                    // 36-44MB (no aliasing)
    ushort_t* Zb    = (ushort_t*)(ws + 5 * M1);

    prep_all<<<dim3(1024, 15), 256, 0, stream>>>(
        Qin, Kin, Vin, WQw, WKw, WVw, WOw,
        Qbin, Kbin, Vbin,
        wqkv, wqkv + (size_t)1024 * 1024, wqkv + (size_t)2 * 1024 * 1024, wob,
        attn_raw, (float*)d_out, sumexp, corr);

    gemm_qkv<<<dim3(48, 16), 256, 0, stream>>>(
        Qbin, Kbin, Vbin, wqkv, WQb, WKb, WVb, qbb, kbb, vt);

    attn_mfma<<<dim3(256, 3), 512, 0, stream>>>(qbb, kbb, vt, attn_raw, sumexp);

    corr_kernel<<<64, 256, 0, stream>>>(sumexp, vt, corr);
    convert_Z<<<2048, 256, 0, stream>>>(attn_raw, corr, Zb);

    gemm_out<<<dim3(16, 16), 256, 0, stream>>>(Zb, wob, WOb, (float*)d_out);
}